// Round 6
// baseline (261.959 us; speedup 1.0000x reference)
//
#include <hip/hip_runtime.h>

typedef unsigned short ushort_t;
typedef _Float16 half_t;
typedef __attribute__((ext_vector_type(2))) _Float16 half2_t;
typedef __attribute__((ext_vector_type(8))) _Float16 half8_t;
typedef __attribute__((ext_vector_type(2))) __fp16 fp16x2;
typedef __attribute__((ext_vector_type(2))) float fx2;
typedef __attribute__((ext_vector_type(4))) float floatx4;

#define LOG2E 1.4426950408889634f
#define LN2   0.6931471805599453f

__device__ __forceinline__ float exp2_(float x) {
#if __has_builtin(__builtin_amdgcn_exp2f)
    return __builtin_amdgcn_exp2f(x);
#else
    return exp2f(x);
#endif
}

__device__ __forceinline__ half2_t cvt_pk_f16(float a, float b) {
    auto r = __builtin_amdgcn_cvt_pkrtz(a, b);
    return __builtin_bit_cast(half2_t, r);
}

__device__ __forceinline__ float fdot2_(half2_t a, half2_t b) {
#if __has_builtin(__builtin_amdgcn_fdot2)
    return __builtin_amdgcn_fdot2(__builtin_bit_cast(fp16x2, a),
                                  __builtin_bit_cast(fp16x2, b), 0.0f, false);
#else
    return (float)a.x * (float)b.x + (float)a.y * (float)b.y;
#endif
}

// packed mish in log2-domain: input t0 = x*log2e, output = mish(x)/ln2
__device__ __forceinline__ fx2 mish2(fx2 t0) {
    fx2 one = {1.0f, 1.0f};
    fx2 m2  = {-2.0f, -2.0f};
    fx2 u   = {exp2_(t0.x), exp2_(t0.y)};
    fx2 s   = u + one;
    fx2 wv  = __builtin_elementwise_fma(s, s, one);     // e^2x+2e^x+2
    fx2 rr  = {__builtin_amdgcn_rcpf(wv.x), __builtin_amdgcn_rcpf(wv.y)};
    fx2 v   = __builtin_elementwise_fma(rr, m2, one);   // tanh(softplus)
    return t0 * v;
}

// sum across each 16-lane row, pure VALU (DPP), no LDS
__device__ __forceinline__ float dpp_sum16(float v) {
    int x = __float_as_int(v);
    v += __int_as_float(__builtin_amdgcn_update_dpp(0, x, 0xB1, 0xF, 0xF, true));
    x = __float_as_int(v);
    v += __int_as_float(__builtin_amdgcn_update_dpp(0, x, 0x4E, 0xF, 0xF, true));
    x = __float_as_int(v);
    v += __int_as_float(__builtin_amdgcn_update_dpp(0, x, 0x124, 0xF, 0xF, true));
    x = __float_as_int(v);
    v += __int_as_float(__builtin_amdgcn_update_dpp(0, x, 0x128, 0xF, 0xF, true));
    return v;
}

// ---------------- prep (unchanged) ----------------
__global__ __launch_bounds__(256) void prep_kernel(
        const float* __restrict__ state,
        const float* __restrict__ action,
        const float* __restrict__ W1,
        const float* __restrict__ W2,
        float* __restrict__ obsWp,
        half_t* __restrict__ actW,
        half_t* __restrict__ W2T,
        float* __restrict__ out) {
    int bid = blockIdx.x;
    int t = threadIdx.x;
    if (bid < 512) {
        int bg = bid >> 3;
        int kc = bid & 7;
        int bs = bg * 8;
        const float* w1p = W1 + (size_t)(kc * 64) * 256 + t;
        const float* stp = state + (size_t)bs * 512 + kc * 64;
        float acc[8];
#pragma unroll
        for (int bb = 0; bb < 8; ++bb) acc[bb] = 0.f;
#pragma unroll 4
        for (int f = 0; f < 64; ++f) {
            float w = w1p[f * 256];
#pragma unroll
            for (int bb = 0; bb < 8; ++bb)
                acc[bb] = fmaf(stp[bb * 512 + f], w, acc[bb]);
        }
#pragma unroll
        for (int bb = 0; bb < 8; ++bb)
            obsWp[(size_t)kc * 131072 + (bs + bb) * 256 + t] = acc[bb];
    } else if (bid < 1536) {
        int idx = bid - 512;
        int j = idx & 7;
        int b0 = (idx >> 3) * 4;
        const float* W1a = W1 + (size_t)(512 + j * 16) * 256;
        float wv[16];
#pragma unroll
        for (int a = 0; a < 16; ++a) wv[a] = W1a[a * 256 + t];
#pragma unroll
        for (int bb = 0; bb < 4; ++bb) {
            int b = b0 + bb;
            const float* acp = action + (size_t)b * 128;
            float acc[8];
#pragma unroll
            for (int n = 0; n < 8; ++n) acc[n] = 0.f;
#pragma unroll
            for (int a = 0; a < 16; ++a) {
#pragma unroll
                for (int n = 0; n < 8; ++n)
                    acc[n] = fmaf(acp[n * 16 + a], wv[a], acc[n]);
            }
#pragma unroll
            for (int n = 0; n < 8; ++n)
                actW[(((size_t)b * 8 + n) * 8 + j) * 256 + t] = (half_t)(acc[n] * LOG2E);
        }
    } else {
        int blk = bid - 1536;
        if (blk < 16) {
            out[blk * 512 + t] = 0.0f;
            out[blk * 512 + 256 + t] = 0.0f;
        }
        int n = blk * 8 + (t >> 5);
        int klo = t & 31;
#pragma unroll
        for (int kk = 0; kk < 8; ++kk) {
            int k = kk * 32 + klo;
            W2T[n * 256 + k] = (half_t)W2[k * 256 + n];
        }
    }
}

// ---------------- main: quarter pipeline, 3 blocks/CU target ----------------
// 16 s per block split into 4 quarters of 4 s (M=32 rows, 2 mt-tiles, acc=16
// regs). Two waves share each s: wave nb=0 builds n=0..3, wave nb=4 adds a
// 4-term act prefix then builds n=4..7. Per-ks interleave (R2-proven): build
// step on even ks, one epilogue idx per ks. bpre dropped (L1 serves ks=0,1).
// LDS ~39.4 KB + <=85 regs via __launch_bounds__(512,6) -> 3 blocks/CU.
// All register arrays are named locals with unroll-constant indices (R3/R4:
// anything else spills to scratch; check = FETCH_SIZE stays ~11.4 MB).
#define CHUNK_US 528
#define UNROLL_ _Pragma("unroll")

#define GATHERQ(AV, PR, QTR)                                                   \
  { int s_ = (QTR) * 4 + siq;                                                  \
    UNROLL_ for (int k = 0; k < 4; ++k) {                                      \
      int p_ = perm_s[s_ * 8 + nb + k];                                        \
      AV[k] = *reinterpret_cast<const uint2*>(actg + (p_ * 8 + nb + k) * 256); \
    }                                                                          \
    if (nb) {                                                                  \
      UNROLL_ for (int k = 0; k < 4; ++k) {                                    \
        int p_ = perm_s[s_ * 8 + k];                                           \
        PR[k] = *reinterpret_cast<const uint2*>(actg + (p_ * 8 + k) * 256);    \
      }                                                                        \
    } }

// one quarter phase: K(RD)->ACC, optional epilogue of ACCP -> qpart[QH],
// optional build of next quarter (AV/PR) -> DSTP. EPF/BUILDF literal.
#define KPHASE(RD, ACC, EPF, ACCP, QH, BUILDF, AV, PR, DSTP)                   \
  { UNROLL_ for (int mt = 0; mt < 2; ++mt) {                                   \
      UNROLL_ for (int nt = 0; nt < 2; ++nt)                                   \
        ACC[mt][nt] = (floatx4){0.f, 0.f, 0.f, 0.f};                           \
    }                                                                          \
    fx2 r01_ = {ob.x, ob.y};                                                   \
    fx2 r23_ = {ob.z, ob.w};                                                   \
    if ((BUILDF) && nb) {                                                      \
      UNROLL_ for (int k = 0; k < 4; ++k) {                                    \
        half2_t a0_ = __builtin_bit_cast(half2_t, PR[k].x);                    \
        half2_t a1_ = __builtin_bit_cast(half2_t, PR[k].y);                    \
        r01_ += (fx2){(float)a0_.x, (float)a0_.y};                             \
        r23_ += (fx2){(float)a1_.x, (float)a1_.y};                             \
      }                                                                        \
    }                                                                          \
    UNROLL_ for (int ks = 0; ks < 8; ++ks) {                                   \
      half8_t afr0_ = *reinterpret_cast<const half8_t*>((RD) + (0 * 8 + ks) * CHUNK_US); \
      half8_t afr1_ = *reinterpret_cast<const half8_t*>((RD) + (1 * 8 + ks) * CHUNK_US); \
      half8_t bfr0_ = *reinterpret_cast<const half8_t*>(w2base + 0 * 4096 + ks * 32); \
      half8_t bfr1_ = *reinterpret_cast<const half8_t*>(w2base + 1 * 4096 + ks * 32); \
      ACC[0][0] = __builtin_amdgcn_mfma_f32_16x16x32_f16(afr0_, bfr0_, ACC[0][0], 0, 0, 0); \
      ACC[0][1] = __builtin_amdgcn_mfma_f32_16x16x32_f16(afr0_, bfr1_, ACC[0][1], 0, 0, 0); \
      ACC[1][0] = __builtin_amdgcn_mfma_f32_16x16x32_f16(afr1_, bfr0_, ACC[1][0], 0, 0, 0); \
      ACC[1][1] = __builtin_amdgcn_mfma_f32_16x16x32_f16(afr1_, bfr1_, ACC[1][1], 0, 0, 0); \
      if ((BUILDF) && !(ks & 1)) {                                             \
        int jp_ = ks >> 1;                                                     \
        half2_t a0_ = __builtin_bit_cast(half2_t, AV[jp_].x);                  \
        half2_t a1_ = __builtin_bit_cast(half2_t, AV[jp_].y);                  \
        r01_ += (fx2){(float)a0_.x, (float)a0_.y};                             \
        r23_ += (fx2){(float)a1_.x, (float)a1_.y};                             \
        fx2 h01_ = mish2(r01_);                                                \
        fx2 h23_ = mish2(r23_);                                                \
        int row_ = siq * 8 + nb + jp_;                                         \
        int mt2_ = row_ >> 4, lr_ = row_ & 15;                                 \
        uint2 pk_ = make_uint2(                                                \
            __builtin_bit_cast(unsigned, cvt_pk_f16(h01_.x, h01_.y)),          \
            __builtin_bit_cast(unsigned, cvt_pk_f16(h23_.x, h23_.y)));         \
        *reinterpret_cast<uint2*>((DSTP) + mt2_ * 8 * CHUNK_US + lr_ * 8) = pk_; \
      }                                                                        \
      if (EPF) {                                                               \
        int mt_ = ks >> 2, r_ = ks & 3;                                        \
        fx2 t2_ = {ACCP[mt_][0][r_], ACCP[mt_][1][r_]};                        \
        t2_ += b2p;                                                            \
        fx2 hh_ = mish2(t2_);                                                  \
        float part_ = fdot2_(cvt_pk_f16(hh_.x, hh_.y), w3p);                   \
        float sr_ = dpp_sum16(part_);                                          \
        if (lo == 0) qpart[QH][w][mt_ * 16 + q * 4 + r_] = sr_;                \
      }                                                                        \
    } }

__global__ __launch_bounds__(512, 6) void main_kernel(
        const float* __restrict__ obsWp, const half_t* __restrict__ actW,
        const half_t* __restrict__ W2T, const int* __restrict__ perm,
        const float* __restrict__ b1, const float* __restrict__ b2,
        const float* __restrict__ W3, const float* __restrict__ b3,
        float* __restrict__ out) {
    __shared__ __align__(16) ushort_t h1[2][16 * CHUNK_US];  // 33,792 B
    __shared__ __align__(16) float obsb[256];
    __shared__ int perm_s[128];
    __shared__ float qpart[4][8][32];                        // 4 KB

    int t = threadIdx.x;
    int bid = blockIdx.x;
    int b = (bid & 7) * 64 + ((bid >> 3) & 63);   // XCD swizzle
    int sgp = bid >> 9;                            // 0..3
    int s0 = sgp * 16;

    int w = t >> 6;
    int L = t & 63;
    int lo = L & 15;
    int q = L >> 4;
    int siq = w & 3;            // s within quarter (2 waves per s)
    int nb = (w >> 2) * 4;      // n-base for this wave: 0 or 4 (wave-uniform)

    const half_t* w2base = W2T + ((size_t)(w * 32 + lo)) * 256 + q * 8;

    int col0 = w * 32 + lo;
    int col1 = col0 + 16;
    fx2 b2p = {b2[col0] * LOG2E, b2[col1] * LOG2E};
    half2_t w3p = cvt_pk_f16(W3[col0] * LN2, W3[col1] * LN2);

    // quarter-0 perm row from global (no barrier dependency)
    const int* prow = perm + ((size_t)b * 64 + s0 + siq) * 8;
    int4 pa0 = *reinterpret_cast<const int4*>(prow);        // j = 0..3
    int4 pa1 = *reinterpret_cast<const int4*>(prow + 4);    // j = 4..7

    if (t < 256) {
        float s = b1[t];
#pragma unroll
        for (int c = 0; c < 8; ++c) s += obsWp[(size_t)c * 131072 + b * 256 + t];
        obsb[t] = s * LOG2E;
    } else if (t < 384) {
        perm_s[t - 256] = perm[((size_t)b * 64 + s0) * 8 + (t - 256)];
    }

    // build geometry: thread covers cols L*4..L*4+3
    int g = L >> 1;
    int ksg = g >> 2;
    int qq = g & 3;
    int halfsel = L & 1;
    const half_t* actg = actW + (size_t)b * 64 * 256 + L * 4;
    int dstoff = qq * 128 + halfsel * 4 + ksg * CHUNK_US;

    // gather quarter 0 NOW (in flight across B0); static selection on nb
    int pjb0 = nb ? pa1.x : pa0.x, pjb1 = nb ? pa1.y : pa0.y;
    int pjb2 = nb ? pa1.z : pa0.z, pjb3 = nb ? pa1.w : pa0.w;
    uint2 av_a[4], pr_a[4];
    uint2 av_b[4], pr_b[4];
    av_a[0] = *reinterpret_cast<const uint2*>(actg + (pjb0 * 8 + nb + 0) * 256);
    av_a[1] = *reinterpret_cast<const uint2*>(actg + (pjb1 * 8 + nb + 1) * 256);
    av_a[2] = *reinterpret_cast<const uint2*>(actg + (pjb2 * 8 + nb + 2) * 256);
    av_a[3] = *reinterpret_cast<const uint2*>(actg + (pjb3 * 8 + nb + 3) * 256);
    if (nb) {
        pr_a[0] = *reinterpret_cast<const uint2*>(actg + (pa0.x * 8 + 0) * 256);
        pr_a[1] = *reinterpret_cast<const uint2*>(actg + (pa0.y * 8 + 1) * 256);
        pr_a[2] = *reinterpret_cast<const uint2*>(actg + (pa0.z * 8 + 2) * 256);
        pr_a[3] = *reinterpret_cast<const uint2*>(actg + (pa0.w * 8 + 3) * 256);
    }

    ushort_t* dst0 = h1[0] + dstoff;
    ushort_t* dst1 = h1[1] + dstoff;
    const ushort_t* rd0 = h1[0] + L * 8;
    const ushort_t* rd1 = h1[1] + L * 8;

    __syncthreads();   // B0: obsb/perm_s visible

    float4 ob = *reinterpret_cast<const float4*>(obsb + L * 4);

    // ---- build quarter 0 (standalone) ----
    {
        fx2 r01 = {ob.x, ob.y};
        fx2 r23 = {ob.z, ob.w};
        if (nb) {
#pragma unroll
            for (int k = 0; k < 4; ++k) {
                half2_t a0 = __builtin_bit_cast(half2_t, pr_a[k].x);
                half2_t a1 = __builtin_bit_cast(half2_t, pr_a[k].y);
                r01 += (fx2){(float)a0.x, (float)a0.y};
                r23 += (fx2){(float)a1.x, (float)a1.y};
            }
        }
#pragma unroll
        for (int j = 0; j < 4; ++j) {
            half2_t a0 = __builtin_bit_cast(half2_t, av_a[j].x);
            half2_t a1 = __builtin_bit_cast(half2_t, av_a[j].y);
            r01 += (fx2){(float)a0.x, (float)a0.y};
            r23 += (fx2){(float)a1.x, (float)a1.y};
            fx2 h01 = mish2(r01);
            fx2 h23 = mish2(r23);
            int row = siq * 8 + nb + j;
            int mt2 = row >> 4, lr = row & 15;
            uint2 pk = make_uint2(__builtin_bit_cast(unsigned, cvt_pk_f16(h01.x, h01.y)),
                                  __builtin_bit_cast(unsigned, cvt_pk_f16(h23.x, h23.y)));
            *reinterpret_cast<uint2*>(dst0 + mt2 * 8 * CHUNK_US + lr * 8) = pk;
        }
    }

    // gather quarter 1 (perm_s valid after B0); in flight across B1
    GATHERQ(av_b, pr_b, 1)

    __syncthreads();   // B1: h1[0] ready

    floatx4 accA[2][2], accB[2][2];

    // ---- P0: K(q0,buf0) || build(q1 -> buf1) ----
    KPHASE(rd0, accA, false, accA, 0, true, av_b, pr_b, dst1)

    // gather quarter 2 (in flight across B2, under P1 MFMAs)
    GATHERQ(av_a, pr_a, 2)

    __syncthreads();   // B2: buf1 ready, buf0 consumed

    // ---- P1: K(q1,buf1) || ep(q0) || build(q2 -> buf0) ----
    KPHASE(rd1, accB, true, accA, 0, true, av_a, pr_a, dst0)

    // gather quarter 3
    GATHERQ(av_b, pr_b, 3)

    __syncthreads();   // B3: buf0 ready, buf1 consumed

    // ---- P2: K(q2,buf0) || ep(q1) || build(q3 -> buf1) ----
    KPHASE(rd0, accA, true, accB, 1, true, av_b, pr_b, dst1)

    __syncthreads();   // B4: buf1 ready, buf0 consumed

    // ---- P3: K(q3,buf1) || ep(q2) ----
    KPHASE(rd1, accB, true, accA, 2, false, av_b, pr_b, dst1)

    // ---- ep(q3): wave-local, no barrier needed ----
#pragma unroll
    for (int idx = 0; idx < 8; ++idx) {
        int mt = idx >> 2, r = idx & 3;
        fx2 t2 = {accB[mt][0][r], accB[mt][1][r]};
        t2 += b2p;
        fx2 hh = mish2(t2);
        float part = fdot2_(cvt_pk_f16(hh.x, hh.y), w3p);
        float s = dpp_sum16(part);
        if (lo == 0) qpart[3][w][mt * 16 + q * 4 + r] = s;
    }
    __syncthreads();   // B5: all qpart visible

    // ---- final: reduce 8 waves, perm-gather, atomic ----
    if (t < 16) {
        int i = t & 7, gg = t >> 3;
        float p = 0.f;
#pragma unroll
        for (int sl = 0; sl < 8; ++sl) {
            int s = gg * 8 + sl;
            int k = perm_s[s * 8 + i];
            int row = (s & 3) * 8 + k;
            float qv = b3[0];
#pragma unroll
            for (int ww = 0; ww < 8; ++ww) qv += qpart[s >> 2][ww][row];
            p += qv;
        }
        p *= (1.0f / 64.0f);
        atomicAdd(&out[b * 8 + i], p);
        atomicAdd(&out[4096 + b * 8 + i], p);
    }
}

extern "C" void kernel_launch(void* const* d_in, const int* in_sizes, int n_in,
                              void* d_out, int out_size, void* d_ws, size_t ws_size,
                              hipStream_t stream) {
    const float* state  = (const float*)d_in[0];
    const float* action = (const float*)d_in[1];
    const float* W1     = (const float*)d_in[2];
    const float* b1     = (const float*)d_in[3];
    const float* W2     = (const float*)d_in[4];
    const float* b2     = (const float*)d_in[5];
    const float* W3     = (const float*)d_in[6];
    const float* b3     = (const float*)d_in[7];
    const int*   perm   = (const int*)d_in[8];
    float* out = (float*)d_out;

    char* ws = (char*)d_ws;
    float*  obsWp = (float*)ws;                          // 8*512*256*4 = 4 MB
    half_t* actW  = (half_t*)(ws + 4194304);             // 16 MB
    half_t* W2T   = (half_t*)(ws + 4194304 + 16777216);  // 128 KB

    prep_kernel<<<1568, 256, 0, stream>>>(state, action, W1, W2, obsWp, actW, W2T, out);
    main_kernel<<<2048, 512, 0, stream>>>(obsWp, actW, W2T, perm, b1, b2, W3, b3, out);
}

// Round 7
// 182.013 us; speedup vs baseline: 1.4392x; 1.4392x over previous
//
#include <hip/hip_runtime.h>

typedef unsigned short ushort_t;
typedef _Float16 half_t;
typedef __attribute__((ext_vector_type(2))) _Float16 half2_t;
typedef __attribute__((ext_vector_type(8))) _Float16 half8_t;
typedef __attribute__((ext_vector_type(2))) __fp16 fp16x2;
typedef __attribute__((ext_vector_type(2))) float fx2;
typedef __attribute__((ext_vector_type(4))) float floatx4;

#define LOG2E 1.4426950408889634f
#define LN2   0.6931471805599453f

__device__ __forceinline__ float exp2_(float x) {
#if __has_builtin(__builtin_amdgcn_exp2f)
    return __builtin_amdgcn_exp2f(x);
#else
    return exp2f(x);
#endif
}

__device__ __forceinline__ half2_t cvt_pk_f16(float a, float b) {
    auto r = __builtin_amdgcn_cvt_pkrtz(a, b);
    return __builtin_bit_cast(half2_t, r);
}

__device__ __forceinline__ float fdot2_(half2_t a, half2_t b) {
#if __has_builtin(__builtin_amdgcn_fdot2)
    return __builtin_amdgcn_fdot2(__builtin_bit_cast(fp16x2, a),
                                  __builtin_bit_cast(fp16x2, b), 0.0f, false);
#else
    return (float)a.x * (float)b.x + (float)a.y * (float)b.y;
#endif
}

// packed mish in log2-domain: input t0 = x*log2e, output = mish(x)/ln2
__device__ __forceinline__ fx2 mish2(fx2 t0) {
    fx2 one = {1.0f, 1.0f};
    fx2 m2  = {-2.0f, -2.0f};
    fx2 u   = {exp2_(t0.x), exp2_(t0.y)};
    fx2 s   = u + one;
    fx2 wv  = __builtin_elementwise_fma(s, s, one);     // e^2x+2e^x+2
    fx2 rr  = {__builtin_amdgcn_rcpf(wv.x), __builtin_amdgcn_rcpf(wv.y)};
    fx2 v   = __builtin_elementwise_fma(rr, m2, one);   // tanh(softplus)
    return t0 * v;
}

// sum across each 16-lane row, pure VALU (DPP), no LDS
__device__ __forceinline__ float dpp_sum16(float v) {
    int x = __float_as_int(v);
    v += __int_as_float(__builtin_amdgcn_update_dpp(0, x, 0xB1, 0xF, 0xF, true));
    x = __float_as_int(v);
    v += __int_as_float(__builtin_amdgcn_update_dpp(0, x, 0x4E, 0xF, 0xF, true));
    x = __float_as_int(v);
    v += __int_as_float(__builtin_amdgcn_update_dpp(0, x, 0x124, 0xF, 0xF, true));
    x = __float_as_int(v);
    v += __int_as_float(__builtin_amdgcn_update_dpp(0, x, 0x128, 0xF, 0xF, true));
    return v;
}

// ---------------- prep (unchanged) ----------------
__global__ __launch_bounds__(256) void prep_kernel(
        const float* __restrict__ state,
        const float* __restrict__ action,
        const float* __restrict__ W1,
        const float* __restrict__ W2,
        float* __restrict__ obsWp,
        half_t* __restrict__ actW,
        half_t* __restrict__ W2T,
        float* __restrict__ out) {
    int bid = blockIdx.x;
    int t = threadIdx.x;
    if (bid < 512) {
        int bg = bid >> 3;
        int kc = bid & 7;
        int bs = bg * 8;
        const float* w1p = W1 + (size_t)(kc * 64) * 256 + t;
        const float* stp = state + (size_t)bs * 512 + kc * 64;
        float acc[8];
#pragma unroll
        for (int bb = 0; bb < 8; ++bb) acc[bb] = 0.f;
#pragma unroll 4
        for (int f = 0; f < 64; ++f) {
            float w = w1p[f * 256];
#pragma unroll
            for (int bb = 0; bb < 8; ++bb)
                acc[bb] = fmaf(stp[bb * 512 + f], w, acc[bb]);
        }
#pragma unroll
        for (int bb = 0; bb < 8; ++bb)
            obsWp[(size_t)kc * 131072 + (bs + bb) * 256 + t] = acc[bb];
    } else if (bid < 1536) {
        int idx = bid - 512;
        int j = idx & 7;
        int b0 = (idx >> 3) * 4;
        const float* W1a = W1 + (size_t)(512 + j * 16) * 256;
        float wv[16];
#pragma unroll
        for (int a = 0; a < 16; ++a) wv[a] = W1a[a * 256 + t];
#pragma unroll
        for (int bb = 0; bb < 4; ++bb) {
            int b = b0 + bb;
            const float* acp = action + (size_t)b * 128;
            float acc[8];
#pragma unroll
            for (int n = 0; n < 8; ++n) acc[n] = 0.f;
#pragma unroll
            for (int a = 0; a < 16; ++a) {
#pragma unroll
                for (int n = 0; n < 8; ++n)
                    acc[n] = fmaf(acp[n * 16 + a], wv[a], acc[n]);
            }
#pragma unroll
            for (int n = 0; n < 8; ++n)
                actW[(((size_t)b * 8 + n) * 8 + j) * 256 + t] = (half_t)(acc[n] * LOG2E);
        }
    } else {
        int blk = bid - 1536;
        if (blk < 16) {
            out[blk * 512 + t] = 0.0f;
            out[blk * 512 + 256 + t] = 0.0f;
        }
        int n = blk * 8 + (t >> 5);
        int klo = t & 31;
#pragma unroll
        for (int kk = 0; kk < 8; ++kk) {
            int k = kk * 32 + klo;
            W2T[n * 256 + k] = (half_t)W2[k * 256 + n];
        }
    }
}

// ---------------- main: quarter pipeline @ LB(512,4) ----------------
// R7 = R6 with ONE change: __launch_bounds__(512,6) -> (512,4). R6's forced
// 85-reg cap spilled ~650 B/thread (FETCH 347 MB); the body actually needs
// ~110-120 regs transiently. At LB(512,4) the allocator is uncapped below
// 128 -> no spill; occupancy is then resource-determined: ~72 unified regs
// -> 7 waves/SIMD possible, LDS 39.4 KB -> 4 blocks possible, integral
// blocks -> 3 blocks/CU = 24 waves. This is the untested quadrant:
// per-ks interleave (R2-proven) + 24-wave occupancy (R1-level).
#define CHUNK_US 528
#define UNROLL_ _Pragma("unroll")

#define GATHERQ(AV, PR, QTR)                                                   \
  { int s_ = (QTR) * 4 + siq;                                                  \
    UNROLL_ for (int k = 0; k < 4; ++k) {                                      \
      int p_ = perm_s[s_ * 8 + nb + k];                                        \
      AV[k] = *reinterpret_cast<const uint2*>(actg + (p_ * 8 + nb + k) * 256); \
    }                                                                          \
    if (nb) {                                                                  \
      UNROLL_ for (int k = 0; k < 4; ++k) {                                    \
        int p_ = perm_s[s_ * 8 + k];                                           \
        PR[k] = *reinterpret_cast<const uint2*>(actg + (p_ * 8 + k) * 256);    \
      }                                                                        \
    } }

// one quarter phase: K(RD)->ACC, optional epilogue of ACCP -> qpart[QH],
// optional build of next quarter (AV/PR) -> DSTP. EPF/BUILDF literal.
#define KPHASE(RD, ACC, EPF, ACCP, QH, BUILDF, AV, PR, DSTP)                   \
  { UNROLL_ for (int mt = 0; mt < 2; ++mt) {                                   \
      UNROLL_ for (int nt = 0; nt < 2; ++nt)                                   \
        ACC[mt][nt] = (floatx4){0.f, 0.f, 0.f, 0.f};                           \
    }                                                                          \
    fx2 r01_ = {ob.x, ob.y};                                                   \
    fx2 r23_ = {ob.z, ob.w};                                                   \
    if ((BUILDF) && nb) {                                                      \
      UNROLL_ for (int k = 0; k < 4; ++k) {                                    \
        half2_t a0_ = __builtin_bit_cast(half2_t, PR[k].x);                    \
        half2_t a1_ = __builtin_bit_cast(half2_t, PR[k].y);                    \
        r01_ += (fx2){(float)a0_.x, (float)a0_.y};                             \
        r23_ += (fx2){(float)a1_.x, (float)a1_.y};                             \
      }                                                                        \
    }                                                                          \
    UNROLL_ for (int ks = 0; ks < 8; ++ks) {                                   \
      half8_t afr0_ = *reinterpret_cast<const half8_t*>((RD) + (0 * 8 + ks) * CHUNK_US); \
      half8_t afr1_ = *reinterpret_cast<const half8_t*>((RD) + (1 * 8 + ks) * CHUNK_US); \
      half8_t bfr0_ = *reinterpret_cast<const half8_t*>(w2base + 0 * 4096 + ks * 32); \
      half8_t bfr1_ = *reinterpret_cast<const half8_t*>(w2base + 1 * 4096 + ks * 32); \
      ACC[0][0] = __builtin_amdgcn_mfma_f32_16x16x32_f16(afr0_, bfr0_, ACC[0][0], 0, 0, 0); \
      ACC[0][1] = __builtin_amdgcn_mfma_f32_16x16x32_f16(afr0_, bfr1_, ACC[0][1], 0, 0, 0); \
      ACC[1][0] = __builtin_amdgcn_mfma_f32_16x16x32_f16(afr1_, bfr0_, ACC[1][0], 0, 0, 0); \
      ACC[1][1] = __builtin_amdgcn_mfma_f32_16x16x32_f16(afr1_, bfr1_, ACC[1][1], 0, 0, 0); \
      if ((BUILDF) && !(ks & 1)) {                                             \
        int jp_ = ks >> 1;                                                     \
        half2_t a0_ = __builtin_bit_cast(half2_t, AV[jp_].x);                  \
        half2_t a1_ = __builtin_bit_cast(half2_t, AV[jp_].y);                  \
        r01_ += (fx2){(float)a0_.x, (float)a0_.y};                             \
        r23_ += (fx2){(float)a1_.x, (float)a1_.y};                             \
        fx2 h01_ = mish2(r01_);                                                \
        fx2 h23_ = mish2(r23_);                                                \
        int row_ = siq * 8 + nb + jp_;                                         \
        int mt2_ = row_ >> 4, lr_ = row_ & 15;                                 \
        uint2 pk_ = make_uint2(                                                \
            __builtin_bit_cast(unsigned, cvt_pk_f16(h01_.x, h01_.y)),          \
            __builtin_bit_cast(unsigned, cvt_pk_f16(h23_.x, h23_.y)));         \
        *reinterpret_cast<uint2*>((DSTP) + mt2_ * 8 * CHUNK_US + lr_ * 8) = pk_; \
      }                                                                        \
      if (EPF) {                                                               \
        int mt_ = ks >> 2, r_ = ks & 3;                                        \
        fx2 t2_ = {ACCP[mt_][0][r_], ACCP[mt_][1][r_]};                        \
        t2_ += b2p;                                                            \
        fx2 hh_ = mish2(t2_);                                                  \
        float part_ = fdot2_(cvt_pk_f16(hh_.x, hh_.y), w3p);                   \
        float sr_ = dpp_sum16(part_);                                          \
        if (lo == 0) qpart[QH][w][mt_ * 16 + q * 4 + r_] = sr_;                \
      }                                                                        \
    } }

__global__ __launch_bounds__(512, 4) void main_kernel(
        const float* __restrict__ obsWp, const half_t* __restrict__ actW,
        const half_t* __restrict__ W2T, const int* __restrict__ perm,
        const float* __restrict__ b1, const float* __restrict__ b2,
        const float* __restrict__ W3, const float* __restrict__ b3,
        float* __restrict__ out) {
    __shared__ __align__(16) ushort_t h1[2][16 * CHUNK_US];  // 33,792 B
    __shared__ __align__(16) float obsb[256];
    __shared__ int perm_s[128];
    __shared__ float qpart[4][8][32];                        // 4 KB

    int t = threadIdx.x;
    int bid = blockIdx.x;
    int b = (bid & 7) * 64 + ((bid >> 3) & 63);   // XCD swizzle
    int sgp = bid >> 9;                            // 0..3
    int s0 = sgp * 16;

    int w = t >> 6;
    int L = t & 63;
    int lo = L & 15;
    int q = L >> 4;
    int siq = w & 3;            // s within quarter (2 waves per s)
    int nb = (w >> 2) * 4;      // n-base for this wave: 0 or 4 (wave-uniform)

    const half_t* w2base = W2T + ((size_t)(w * 32 + lo)) * 256 + q * 8;

    int col0 = w * 32 + lo;
    int col1 = col0 + 16;
    fx2 b2p = {b2[col0] * LOG2E, b2[col1] * LOG2E};
    half2_t w3p = cvt_pk_f16(W3[col0] * LN2, W3[col1] * LN2);

    // quarter-0 perm row from global (no barrier dependency)
    const int* prow = perm + ((size_t)b * 64 + s0 + siq) * 8;
    int4 pa0 = *reinterpret_cast<const int4*>(prow);        // j = 0..3
    int4 pa1 = *reinterpret_cast<const int4*>(prow + 4);    // j = 4..7

    if (t < 256) {
        float s = b1[t];
#pragma unroll
        for (int c = 0; c < 8; ++c) s += obsWp[(size_t)c * 131072 + b * 256 + t];
        obsb[t] = s * LOG2E;
    } else if (t < 384) {
        perm_s[t - 256] = perm[((size_t)b * 64 + s0) * 8 + (t - 256)];
    }

    // build geometry: thread covers cols L*4..L*4+3
    int g = L >> 1;
    int ksg = g >> 2;
    int qq = g & 3;
    int halfsel = L & 1;
    const half_t* actg = actW + (size_t)b * 64 * 256 + L * 4;
    int dstoff = qq * 128 + halfsel * 4 + ksg * CHUNK_US;

    // gather quarter 0 NOW (in flight across B0); static selection on nb
    int pjb0 = nb ? pa1.x : pa0.x, pjb1 = nb ? pa1.y : pa0.y;
    int pjb2 = nb ? pa1.z : pa0.z, pjb3 = nb ? pa1.w : pa0.w;
    uint2 av_a[4], pr_a[4];
    uint2 av_b[4], pr_b[4];
    av_a[0] = *reinterpret_cast<const uint2*>(actg + (pjb0 * 8 + nb + 0) * 256);
    av_a[1] = *reinterpret_cast<const uint2*>(actg + (pjb1 * 8 + nb + 1) * 256);
    av_a[2] = *reinterpret_cast<const uint2*>(actg + (pjb2 * 8 + nb + 2) * 256);
    av_a[3] = *reinterpret_cast<const uint2*>(actg + (pjb3 * 8 + nb + 3) * 256);
    if (nb) {
        pr_a[0] = *reinterpret_cast<const uint2*>(actg + (pa0.x * 8 + 0) * 256);
        pr_a[1] = *reinterpret_cast<const uint2*>(actg + (pa0.y * 8 + 1) * 256);
        pr_a[2] = *reinterpret_cast<const uint2*>(actg + (pa0.z * 8 + 2) * 256);
        pr_a[3] = *reinterpret_cast<const uint2*>(actg + (pa0.w * 8 + 3) * 256);
    }

    ushort_t* dst0 = h1[0] + dstoff;
    ushort_t* dst1 = h1[1] + dstoff;
    const ushort_t* rd0 = h1[0] + L * 8;
    const ushort_t* rd1 = h1[1] + L * 8;

    __syncthreads();   // B0: obsb/perm_s visible

    float4 ob = *reinterpret_cast<const float4*>(obsb + L * 4);

    // ---- build quarter 0 (standalone) ----
    {
        fx2 r01 = {ob.x, ob.y};
        fx2 r23 = {ob.z, ob.w};
        if (nb) {
#pragma unroll
            for (int k = 0; k < 4; ++k) {
                half2_t a0 = __builtin_bit_cast(half2_t, pr_a[k].x);
                half2_t a1 = __builtin_bit_cast(half2_t, pr_a[k].y);
                r01 += (fx2){(float)a0.x, (float)a0.y};
                r23 += (fx2){(float)a1.x, (float)a1.y};
            }
        }
#pragma unroll
        for (int j = 0; j < 4; ++j) {
            half2_t a0 = __builtin_bit_cast(half2_t, av_a[j].x);
            half2_t a1 = __builtin_bit_cast(half2_t, av_a[j].y);
            r01 += (fx2){(float)a0.x, (float)a0.y};
            r23 += (fx2){(float)a1.x, (float)a1.y};
            fx2 h01 = mish2(r01);
            fx2 h23 = mish2(r23);
            int row = siq * 8 + nb + j;
            int mt2 = row >> 4, lr = row & 15;
            uint2 pk = make_uint2(__builtin_bit_cast(unsigned, cvt_pk_f16(h01.x, h01.y)),
                                  __builtin_bit_cast(unsigned, cvt_pk_f16(h23.x, h23.y)));
            *reinterpret_cast<uint2*>(dst0 + mt2 * 8 * CHUNK_US + lr * 8) = pk;
        }
    }

    // gather quarter 1 (perm_s valid after B0); in flight across B1
    GATHERQ(av_b, pr_b, 1)

    __syncthreads();   // B1: h1[0] ready

    floatx4 accA[2][2], accB[2][2];

    // ---- P0: K(q0,buf0) || build(q1 -> buf1) ----
    KPHASE(rd0, accA, false, accA, 0, true, av_b, pr_b, dst1)

    // gather quarter 2 (in flight across B2, under P1 MFMAs)
    GATHERQ(av_a, pr_a, 2)

    __syncthreads();   // B2: buf1 ready, buf0 consumed

    // ---- P1: K(q1,buf1) || ep(q0) || build(q2 -> buf0) ----
    KPHASE(rd1, accB, true, accA, 0, true, av_a, pr_a, dst0)

    // gather quarter 3
    GATHERQ(av_b, pr_b, 3)

    __syncthreads();   // B3: buf0 ready, buf1 consumed

    // ---- P2: K(q2,buf0) || ep(q1) || build(q3 -> buf1) ----
    KPHASE(rd0, accA, true, accB, 1, true, av_b, pr_b, dst1)

    __syncthreads();   // B4: buf1 ready, buf0 consumed

    // ---- P3: K(q3,buf1) || ep(q2) ----
    KPHASE(rd1, accB, true, accA, 2, false, av_b, pr_b, dst1)

    // ---- ep(q3): wave-local, no barrier needed ----
#pragma unroll
    for (int idx = 0; idx < 8; ++idx) {
        int mt = idx >> 2, r = idx & 3;
        fx2 t2 = {accB[mt][0][r], accB[mt][1][r]};
        t2 += b2p;
        fx2 hh = mish2(t2);
        float part = fdot2_(cvt_pk_f16(hh.x, hh.y), w3p);
        float s = dpp_sum16(part);
        if (lo == 0) qpart[3][w][mt * 16 + q * 4 + r] = s;
    }
    __syncthreads();   // B5: all qpart visible

    // ---- final: reduce 8 waves, perm-gather, atomic ----
    if (t < 16) {
        int i = t & 7, gg = t >> 3;
        float p = 0.f;
#pragma unroll
        for (int sl = 0; sl < 8; ++sl) {
            int s = gg * 8 + sl;
            int k = perm_s[s * 8 + i];
            int row = (s & 3) * 8 + k;
            float qv = b3[0];
#pragma unroll
            for (int ww = 0; ww < 8; ++ww) qv += qpart[s >> 2][ww][row];
            p += qv;
        }
        p *= (1.0f / 64.0f);
        atomicAdd(&out[b * 8 + i], p);
        atomicAdd(&out[4096 + b * 8 + i], p);
    }
}

extern "C" void kernel_launch(void* const* d_in, const int* in_sizes, int n_in,
                              void* d_out, int out_size, void* d_ws, size_t ws_size,
                              hipStream_t stream) {
    const float* state  = (const float*)d_in[0];
    const float* action = (const float*)d_in[1];
    const float* W1     = (const float*)d_in[2];
    const float* b1     = (const float*)d_in[3];
    const float* W2     = (const float*)d_in[4];
    const float* b2     = (const float*)d_in[5];
    const float* W3     = (const float*)d_in[6];
    const float* b3     = (const float*)d_in[7];
    const int*   perm   = (const int*)d_in[8];
    float* out = (float*)d_out;

    char* ws = (char*)d_ws;
    float*  obsWp = (float*)ws;                          // 8*512*256*4 = 4 MB
    half_t* actW  = (half_t*)(ws + 4194304);             // 16 MB
    half_t* W2T   = (half_t*)(ws + 4194304 + 16777216);  // 128 KB

    prep_kernel<<<1568, 256, 0, stream>>>(state, action, W1, W2, obsWp, actW, W2T, out);
    main_kernel<<<2048, 512, 0, stream>>>(obsWp, actW, W2T, perm, b1, b2, W3, b3, out);
}

// Round 8
// 180.836 us; speedup vs baseline: 1.4486x; 1.0065x over previous
//
#include <hip/hip_runtime.h>

typedef unsigned short ushort_t;
typedef _Float16 half_t;
typedef __attribute__((ext_vector_type(2))) _Float16 half2_t;
typedef __attribute__((ext_vector_type(8))) _Float16 half8_t;
typedef __attribute__((ext_vector_type(2))) __fp16 fp16x2;
typedef __attribute__((ext_vector_type(2))) float fx2;
typedef __attribute__((ext_vector_type(4))) float floatx4;

#define LOG2E 1.4426950408889634f
#define LN2   0.6931471805599453f

__device__ __forceinline__ float exp2_(float x) {
#if __has_builtin(__builtin_amdgcn_exp2f)
    return __builtin_amdgcn_exp2f(x);
#else
    return exp2f(x);
#endif
}

__device__ __forceinline__ half2_t cvt_pk_f16(float a, float b) {
    auto r = __builtin_amdgcn_cvt_pkrtz(a, b);
    return __builtin_bit_cast(half2_t, r);
}

__device__ __forceinline__ float fdot2_(half2_t a, half2_t b) {
#if __has_builtin(__builtin_amdgcn_fdot2)
    return __builtin_amdgcn_fdot2(__builtin_bit_cast(fp16x2, a),
                                  __builtin_bit_cast(fp16x2, b), 0.0f, false);
#else
    return (float)a.x * (float)b.x + (float)a.y * (float)b.y;
#endif
}

// packed mish in log2-domain: input t0 = x*log2e, output = mish(x)/ln2
__device__ __forceinline__ fx2 mish2(fx2 t0) {
    fx2 one = {1.0f, 1.0f};
    fx2 m2  = {-2.0f, -2.0f};
    fx2 u   = {exp2_(t0.x), exp2_(t0.y)};
    fx2 s   = u + one;
    fx2 wv  = __builtin_elementwise_fma(s, s, one);     // e^2x+2e^x+2
    fx2 rr  = {__builtin_amdgcn_rcpf(wv.x), __builtin_amdgcn_rcpf(wv.y)};
    fx2 v   = __builtin_elementwise_fma(rr, m2, one);   // tanh(softplus)
    return t0 * v;
}

// sum across each 16-lane row, pure VALU (DPP), no LDS
__device__ __forceinline__ float dpp_sum16(float v) {
    int x = __float_as_int(v);
    v += __int_as_float(__builtin_amdgcn_update_dpp(0, x, 0xB1, 0xF, 0xF, true));
    x = __float_as_int(v);
    v += __int_as_float(__builtin_amdgcn_update_dpp(0, x, 0x4E, 0xF, 0xF, true));
    x = __float_as_int(v);
    v += __int_as_float(__builtin_amdgcn_update_dpp(0, x, 0x124, 0xF, 0xF, true));
    x = __float_as_int(v);
    v += __int_as_float(__builtin_amdgcn_update_dpp(0, x, 0x128, 0xF, 0xF, true));
    return v;
}

// ---------------- prep (unchanged) ----------------
__global__ __launch_bounds__(256) void prep_kernel(
        const float* __restrict__ state,
        const float* __restrict__ action,
        const float* __restrict__ W1,
        const float* __restrict__ W2,
        float* __restrict__ obsWp,
        half_t* __restrict__ actW,
        half_t* __restrict__ W2T,
        float* __restrict__ out) {
    int bid = blockIdx.x;
    int t = threadIdx.x;
    if (bid < 512) {
        int bg = bid >> 3;
        int kc = bid & 7;
        int bs = bg * 8;
        const float* w1p = W1 + (size_t)(kc * 64) * 256 + t;
        const float* stp = state + (size_t)bs * 512 + kc * 64;
        float acc[8];
#pragma unroll
        for (int bb = 0; bb < 8; ++bb) acc[bb] = 0.f;
#pragma unroll 4
        for (int f = 0; f < 64; ++f) {
            float w = w1p[f * 256];
#pragma unroll
            for (int bb = 0; bb < 8; ++bb)
                acc[bb] = fmaf(stp[bb * 512 + f], w, acc[bb]);
        }
#pragma unroll
        for (int bb = 0; bb < 8; ++bb)
            obsWp[(size_t)kc * 131072 + (bs + bb) * 256 + t] = acc[bb];
    } else if (bid < 1536) {
        int idx = bid - 512;
        int j = idx & 7;
        int b0 = (idx >> 3) * 4;
        const float* W1a = W1 + (size_t)(512 + j * 16) * 256;
        float wv[16];
#pragma unroll
        for (int a = 0; a < 16; ++a) wv[a] = W1a[a * 256 + t];
#pragma unroll
        for (int bb = 0; bb < 4; ++bb) {
            int b = b0 + bb;
            const float* acp = action + (size_t)b * 128;
            float acc[8];
#pragma unroll
            for (int n = 0; n < 8; ++n) acc[n] = 0.f;
#pragma unroll
            for (int a = 0; a < 16; ++a) {
#pragma unroll
                for (int n = 0; n < 8; ++n)
                    acc[n] = fmaf(acp[n * 16 + a], wv[a], acc[n]);
            }
#pragma unroll
            for (int n = 0; n < 8; ++n)
                actW[(((size_t)b * 8 + n) * 8 + j) * 256 + t] = (half_t)(acc[n] * LOG2E);
        }
    } else {
        int blk = bid - 1536;
        if (blk < 16) {
            out[blk * 512 + t] = 0.0f;
            out[blk * 512 + 256 + t] = 0.0f;
        }
        int n = blk * 8 + (t >> 5);
        int klo = t & 31;
#pragma unroll
        for (int kk = 0; kk < 8; ++kk) {
            int k = kk * 32 + klo;
            W2T[n * 256 + k] = (half_t)W2[k * 256 + n];
        }
    }
}

// ---------------- main: persistent 64-s blocks (R2 pipeline x4 sg) ----------------
// grid = 512 = exactly 2 blocks/CU resident, single scheduling round (no
// inter-round drains). Each block loops sg=0..3 over its b's four 16-s groups,
// running the verified R2 two-phase pipeline per sg. Prologue (bpre/b2p/w3p/
// obsb/perm_s) paid once instead of 4x; 3 barriers per sg (B3 -> next build0
// ordering is transitive through B1'). Loop-carried av0 is gathered AFTER ep1
// where both accs are dead -- register peak identical to R2 (R3/R4/R7 lesson:
// never add a live array to a phase holding an acc).
#define CHUNK_US 528

__global__ __launch_bounds__(512, 4) void main_kernel(
        const float* __restrict__ obsWp, const half_t* __restrict__ actW,
        const half_t* __restrict__ W2T, const int* __restrict__ perm,
        const float* __restrict__ b1, const float* __restrict__ b2,
        const float* __restrict__ W3, const float* __restrict__ b3,
        float* __restrict__ out) {
    __shared__ __align__(16) ushort_t h1[2][32 * CHUNK_US];  // 66 KB
    __shared__ __align__(16) float obsb[256];
    __shared__ int perm_s[512];                              // all 64 s x 8 n
    __shared__ float qpart[2][8][64];                        // 4 KB

    int t = threadIdx.x;
    int bid = blockIdx.x;
    int b = (bid & 7) * 64 + ((bid >> 3) & 63);   // XCD swizzle, 512 blocks = all b

    int w = t >> 6;
    int L = t & 63;
    int lo = L & 15;
    int q = L >> 4;

    // ---- prologue: once per block ----
    const half_t* w2base = W2T + ((size_t)(w * 32 + lo)) * 256 + q * 8;
    half8_t bpre[4];
    bpre[0] = *reinterpret_cast<const half8_t*>(w2base + 0 * 4096 + 0 * 32);
    bpre[1] = *reinterpret_cast<const half8_t*>(w2base + 1 * 4096 + 0 * 32);
    bpre[2] = *reinterpret_cast<const half8_t*>(w2base + 0 * 4096 + 1 * 32);
    bpre[3] = *reinterpret_cast<const half8_t*>(w2base + 1 * 4096 + 1 * 32);

    int col0 = w * 32 + lo;
    int col1 = col0 + 16;
    fx2 b2p = {b2[col0] * LOG2E, b2[col1] * LOG2E};
    half2_t w3p = cvt_pk_f16(W3[col0] * LN2, W3[col1] * LN2);
    float b3v = b3[0];

    // sg=0 half-0 perm row direct from global (no barrier dependency)
    const int* prow = perm + ((size_t)b * 64 + w) * 8;
    int4 pa0 = *reinterpret_cast<const int4*>(prow);
    int4 pa1 = *reinterpret_cast<const int4*>(prow + 4);

    if (t < 256) {
        float s = b1[t];
#pragma unroll
        for (int c = 0; c < 8; ++c) s += obsWp[(size_t)c * 131072 + b * 256 + t];
        obsb[t] = s * LOG2E;
    }
    perm_s[t] = perm[(size_t)b * 512 + t];       // all 512 entries

    // build geometry: thread covers cols L*4..L*4+3 of rows (w*8+j)
    int g = L >> 1;
    int ksg = g >> 2;
    int qq = g & 3;
    int halfsel = L & 1;
    const half_t* actg = actW + (size_t)b * 64 * 256 + L * 4;
    int dstoff = qq * 128 + halfsel * 4 + ksg * CHUNK_US;

    // gather sg=0 half-0 act rows NOW (in flight across B0)
    int pj0[8] = {pa0.x, pa0.y, pa0.z, pa0.w, pa1.x, pa1.y, pa1.z, pa1.w};
    uint2 av0[8];
#pragma unroll
    for (int j = 0; j < 8; ++j)
        av0[j] = *reinterpret_cast<const uint2*>(actg + (pj0[j] * 8 + j) * 256);

    __syncthreads();   // B0: obsb/perm_s visible (once per block)

    float4 ob = *reinterpret_cast<const float4*>(obsb + L * 4);

    uint2 av1[8];
    floatx4 acc0[4][2], acc1[4][2];

#pragma unroll 1
    for (int sg = 0; sg < 4; ++sg) {
        // ---- build half 0 of this sg (av0 gathered in prev iteration / prologue) ----
        {
            fx2 r01 = {ob.x, ob.y};
            fx2 r23 = {ob.z, ob.w};
            ushort_t* dst0 = h1[0] + dstoff;
#pragma unroll
            for (int j = 0; j < 8; ++j) {
                half2_t a0 = __builtin_bit_cast(half2_t, av0[j].x);
                half2_t a1 = __builtin_bit_cast(half2_t, av0[j].y);
                r01 += (fx2){(float)a0.x, (float)a0.y};
                r23 += (fx2){(float)a1.x, (float)a1.y};
                fx2 h01 = mish2(r01);
                fx2 h23 = mish2(r23);
                int row = w * 8 + j;
                int mt2 = row >> 4, lr = row & 15;
                uint2 pk = make_uint2(__builtin_bit_cast(unsigned, cvt_pk_f16(h01.x, h01.y)),
                                      __builtin_bit_cast(unsigned, cvt_pk_f16(h23.x, h23.y)));
                *reinterpret_cast<uint2*>(dst0 + mt2 * 8 * CHUNK_US + lr * 8) = pk;
            }
        }

        // gather half-1 act rows (s = sg*16 + 8 + w); in flight across B1
#pragma unroll
        for (int j = 0; j < 8; ++j) {
            int p = perm_s[(sg * 16 + 8 + w) * 8 + j];
            av1[j] = *reinterpret_cast<const uint2*>(actg + (p * 8 + j) * 256);
        }

        __syncthreads();   // B1: h1[0] ready

        // ---- phase 1: K(half0) -> acc0 || build(half1) -> h1[1] ----
#pragma unroll
        for (int mt = 0; mt < 4; ++mt)
#pragma unroll
            for (int nt = 0; nt < 2; ++nt) acc0[mt][nt] = (floatx4){0.f, 0.f, 0.f, 0.f};
        {
            fx2 r01 = {ob.x, ob.y};
            fx2 r23 = {ob.z, ob.w};
            ushort_t* dst1 = h1[1] + dstoff;
            const ushort_t* h1b0 = h1[0] + L * 8;
#pragma unroll
            for (int ks = 0; ks < 8; ++ks) {
                half8_t afr[4];
#pragma unroll
                for (int mt = 0; mt < 4; ++mt)
                    afr[mt] = *reinterpret_cast<const half8_t*>(h1b0 + (mt * 8 + ks) * CHUNK_US);
                half8_t bfr0 = (ks == 0) ? bpre[0] : (ks == 1) ? bpre[2]
                             : *reinterpret_cast<const half8_t*>(w2base + 0 * 4096 + ks * 32);
                half8_t bfr1 = (ks == 0) ? bpre[1] : (ks == 1) ? bpre[3]
                             : *reinterpret_cast<const half8_t*>(w2base + 1 * 4096 + ks * 32);
#pragma unroll
                for (int mt = 0; mt < 4; ++mt) {
                    acc0[mt][0] = __builtin_amdgcn_mfma_f32_16x16x32_f16(afr[mt], bfr0, acc0[mt][0], 0, 0, 0);
                    acc0[mt][1] = __builtin_amdgcn_mfma_f32_16x16x32_f16(afr[mt], bfr1, acc0[mt][1], 0, 0, 0);
                }
                // build1 step j=ks (VALU/trans fills MFMA shadow)
                {
                    half2_t a0 = __builtin_bit_cast(half2_t, av1[ks].x);
                    half2_t a1 = __builtin_bit_cast(half2_t, av1[ks].y);
                    r01 += (fx2){(float)a0.x, (float)a0.y};
                    r23 += (fx2){(float)a1.x, (float)a1.y};
                    fx2 h01 = mish2(r01);
                    fx2 h23 = mish2(r23);
                    int row = w * 8 + ks;
                    int mt2 = row >> 4, lr = row & 15;
                    uint2 pk = make_uint2(__builtin_bit_cast(unsigned, cvt_pk_f16(h01.x, h01.y)),
                                          __builtin_bit_cast(unsigned, cvt_pk_f16(h23.x, h23.y)));
                    *reinterpret_cast<uint2*>(dst1 + mt2 * 8 * CHUNK_US + lr * 8) = pk;
                }
            }
        }
        __syncthreads();   // B2: h1[1] ready, h1[0] consumed

        // ---- phase 2: K(half1) -> acc1 || epilogue(half0) ----
#pragma unroll
        for (int mt = 0; mt < 4; ++mt)
#pragma unroll
            for (int nt = 0; nt < 2; ++nt) acc1[mt][nt] = (floatx4){0.f, 0.f, 0.f, 0.f};
        {
            const ushort_t* h1b1 = h1[1] + L * 8;
#pragma unroll
            for (int ks = 0; ks < 8; ++ks) {
                half8_t afr[4];
#pragma unroll
                for (int mt = 0; mt < 4; ++mt)
                    afr[mt] = *reinterpret_cast<const half8_t*>(h1b1 + (mt * 8 + ks) * CHUNK_US);
                half8_t bfr0 = (ks == 0) ? bpre[0] : (ks == 1) ? bpre[2]
                             : *reinterpret_cast<const half8_t*>(w2base + 0 * 4096 + ks * 32);
                half8_t bfr1 = (ks == 0) ? bpre[1] : (ks == 1) ? bpre[3]
                             : *reinterpret_cast<const half8_t*>(w2base + 1 * 4096 + ks * 32);
#pragma unroll
                for (int mt = 0; mt < 4; ++mt) {
                    acc1[mt][0] = __builtin_amdgcn_mfma_f32_16x16x32_f16(afr[mt], bfr0, acc1[mt][0], 0, 0, 0);
                    acc1[mt][1] = __builtin_amdgcn_mfma_f32_16x16x32_f16(afr[mt], bfr1, acc1[mt][1], 0, 0, 0);
                }
                // epilogue(half0): 2 of 16 (mt,r) values per ks
#pragma unroll
                for (int v = 0; v < 2; ++v) {
                    int idx = ks * 2 + v;
                    int mt = idx >> 2, r = idx & 3;
                    fx2 t2 = {acc0[mt][0][r], acc0[mt][1][r]};
                    t2 += b2p;
                    fx2 hh = mish2(t2);
                    float part = fdot2_(cvt_pk_f16(hh.x, hh.y), w3p);
                    float s = dpp_sum16(part);
                    if (lo == 0) qpart[0][w][mt * 16 + q * 4 + r] = s;
                }
            }
        }
        // ---- epilogue(half1): wave-local, no barrier needed ----
#pragma unroll
        for (int idx = 0; idx < 16; ++idx) {
            int mt = idx >> 2, r = idx & 3;
            fx2 t2 = {acc1[mt][0][r], acc1[mt][1][r]};
            t2 += b2p;
            fx2 hh = mish2(t2);
            float part = fdot2_(cvt_pk_f16(hh.x, hh.y), w3p);
            float s = dpp_sum16(part);
            if (lo == 0) qpart[1][w][mt * 16 + q * 4 + r] = s;
        }

        // gather av0 for next sg HERE: acc0/acc1 both dead -> no register-peak
        // increase; loads fly across B3 + reduce into next build0.
        if (sg < 3) {
#pragma unroll
            for (int j = 0; j < 8; ++j) {
                int p = perm_s[((sg + 1) * 16 + w) * 8 + j];
                av0[j] = *reinterpret_cast<const uint2*>(actg + (p * 8 + j) * 256);
            }
        }

        __syncthreads();   // B3: all qpart visible

        // ---- final: reduce 8 waves, perm-gather, atomic (waves 1-7 proceed) ----
        if (t < 16) {
            int h = t >> 3, i = t & 7;
            float p = 0.f;
#pragma unroll
            for (int sl = 0; sl < 8; ++sl) {
                int k = perm_s[(sg * 16 + h * 8 + sl) * 8 + i];
                int row = sl * 8 + k;
                float qv = b3v;
#pragma unroll
                for (int ww = 0; ww < 8; ++ww) qv += qpart[h][ww][row];
                p += qv;
            }
            p *= (1.0f / 64.0f);
            atomicAdd(&out[b * 8 + i], p);
            atomicAdd(&out[4096 + b * 8 + i], p);
        }
        // no barrier needed before next build0: h1[0] last read pre-B2; qpart
        // next written in phase2' which is after B1'/B2' (reduce finishes first).
    }
}

extern "C" void kernel_launch(void* const* d_in, const int* in_sizes, int n_in,
                              void* d_out, int out_size, void* d_ws, size_t ws_size,
                              hipStream_t stream) {
    const float* state  = (const float*)d_in[0];
    const float* action = (const float*)d_in[1];
    const float* W1     = (const float*)d_in[2];
    const float* b1     = (const float*)d_in[3];
    const float* W2     = (const float*)d_in[4];
    const float* b2     = (const float*)d_in[5];
    const float* W3     = (const float*)d_in[6];
    const float* b3     = (const float*)d_in[7];
    const int*   perm   = (const int*)d_in[8];
    float* out = (float*)d_out;

    char* ws = (char*)d_ws;
    float*  obsWp = (float*)ws;                          // 8*512*256*4 = 4 MB
    half_t* actW  = (half_t*)(ws + 4194304);             // 16 MB
    half_t* W2T   = (half_t*)(ws + 4194304 + 16777216);  // 128 KB

    prep_kernel<<<1568, 256, 0, stream>>>(state, action, W1, W2, obsWp, actW, W2T, out);
    main_kernel<<<512, 512, 0, stream>>>(obsWp, actW, W2T, perm, b1, b2, W3, b3, out);
}

// Round 9
// 164.191 us; speedup vs baseline: 1.5955x; 1.1014x over previous
//
#include <hip/hip_runtime.h>

typedef unsigned short ushort_t;
typedef _Float16 half_t;
typedef __attribute__((ext_vector_type(2))) _Float16 half2_t;
typedef __attribute__((ext_vector_type(8))) _Float16 half8_t;
typedef __attribute__((ext_vector_type(2))) __fp16 fp16x2;
typedef __attribute__((ext_vector_type(2))) float fx2;
typedef __attribute__((ext_vector_type(4))) float floatx4;

#define LOG2E 1.4426950408889634f
#define LN2   0.6931471805599453f

__device__ __forceinline__ float exp2_(float x) {
#if __has_builtin(__builtin_amdgcn_exp2f)
    return __builtin_amdgcn_exp2f(x);
#else
    return exp2f(x);
#endif
}

__device__ __forceinline__ half2_t cvt_pk_f16(float a, float b) {
    auto r = __builtin_amdgcn_cvt_pkrtz(a, b);
    return __builtin_bit_cast(half2_t, r);
}

__device__ __forceinline__ float fdot2_(half2_t a, half2_t b) {
#if __has_builtin(__builtin_amdgcn_fdot2)
    return __builtin_amdgcn_fdot2(__builtin_bit_cast(fp16x2, a),
                                  __builtin_bit_cast(fp16x2, b), 0.0f, false);
#else
    return (float)a.x * (float)b.x + (float)a.y * (float)b.y;
#endif
}

// packed mish in log2-domain: input t0 = x*log2e, output = mish(x)/ln2
__device__ __forceinline__ fx2 mish2(fx2 t0) {
    fx2 one = {1.0f, 1.0f};
    fx2 m2  = {-2.0f, -2.0f};
    fx2 u   = {exp2_(t0.x), exp2_(t0.y)};
    fx2 s   = u + one;
    fx2 wv  = __builtin_elementwise_fma(s, s, one);     // e^2x+2e^x+2
    fx2 rr  = {__builtin_amdgcn_rcpf(wv.x), __builtin_amdgcn_rcpf(wv.y)};
    fx2 v   = __builtin_elementwise_fma(rr, m2, one);   // tanh(softplus)
    return t0 * v;
}

// sum across each 16-lane row, pure VALU (DPP), no LDS
__device__ __forceinline__ float dpp_sum16(float v) {
    int x = __float_as_int(v);
    v += __int_as_float(__builtin_amdgcn_update_dpp(0, x, 0xB1, 0xF, 0xF, true));
    x = __float_as_int(v);
    v += __int_as_float(__builtin_amdgcn_update_dpp(0, x, 0x4E, 0xF, 0xF, true));
    x = __float_as_int(v);
    v += __int_as_float(__builtin_amdgcn_update_dpp(0, x, 0x124, 0xF, 0xF, true));
    x = __float_as_int(v);
    v += __int_as_float(__builtin_amdgcn_update_dpp(0, x, 0x128, 0xF, 0xF, true));
    return v;
}

// ---------------- prep ----------------
// blocks [0,512):      obsW partials: bg=bid>>3 (8 b's), kc=bid&7 (K-chunk of 64)
//                      obsWp[kc][b][t] = sum_{f in chunk} state[b][f]*W1[f][t]
// blocks [512,1536):   actW f16 = (action@W1act)*log2e: idx=bid-512, j=idx&7, b0=(idx>>3)*4
// blocks [1536,1568):  W2T f16 transpose; first 16 also zero `out`
__global__ __launch_bounds__(256) void prep_kernel(
        const float* __restrict__ state,
        const float* __restrict__ action,
        const float* __restrict__ W1,
        const float* __restrict__ W2,
        float* __restrict__ obsWp,
        half_t* __restrict__ actW,
        half_t* __restrict__ W2T,
        float* __restrict__ out) {
    int bid = blockIdx.x;
    int t = threadIdx.x;
    if (bid < 512) {
        int bg = bid >> 3;          // 0..63 -> b = bg*8 .. bg*8+7
        int kc = bid & 7;           // K-chunk, 64 wide
        int bs = bg * 8;
        const float* w1p = W1 + (size_t)(kc * 64) * 256 + t;
        const float* stp = state + (size_t)bs * 512 + kc * 64;  // wave-uniform -> s_load
        float acc[8];
#pragma unroll
        for (int bb = 0; bb < 8; ++bb) acc[bb] = 0.f;
#pragma unroll 4
        for (int f = 0; f < 64; ++f) {
            float w = w1p[f * 256];
#pragma unroll
            for (int bb = 0; bb < 8; ++bb)
                acc[bb] = fmaf(stp[bb * 512 + f], w, acc[bb]);
        }
#pragma unroll
        for (int bb = 0; bb < 8; ++bb)
            obsWp[(size_t)kc * 131072 + (bs + bb) * 256 + t] = acc[bb];
    } else if (bid < 1536) {
        int idx = bid - 512;
        int j = idx & 7;
        int b0 = (idx >> 3) * 4;
        const float* W1a = W1 + (size_t)(512 + j * 16) * 256;
        float wv[16];
#pragma unroll
        for (int a = 0; a < 16; ++a) wv[a] = W1a[a * 256 + t];
#pragma unroll
        for (int bb = 0; bb < 4; ++bb) {
            int b = b0 + bb;
            const float* acp = action + (size_t)b * 128;   // wave-uniform -> s_load
            float acc[8];
#pragma unroll
            for (int n = 0; n < 8; ++n) acc[n] = 0.f;
#pragma unroll
            for (int a = 0; a < 16; ++a) {
#pragma unroll
                for (int n = 0; n < 8; ++n)
                    acc[n] = fmaf(acp[n * 16 + a], wv[a], acc[n]);
            }
#pragma unroll
            for (int n = 0; n < 8; ++n)
                actW[(((size_t)b * 8 + n) * 8 + j) * 256 + t] = (half_t)(acc[n] * LOG2E);
        }
    } else {
        int blk = bid - 1536;             // 0..31
        if (blk < 16) {                   // zero both output copies (8192 floats)
            out[blk * 512 + t] = 0.0f;
            out[blk * 512 + 256 + t] = 0.0f;
        }
        int n = blk * 8 + (t >> 5);
        int klo = t & 31;
#pragma unroll
        for (int kk = 0; kk < 8; ++kk) {
            int k = kk * 32 + klo;
            W2T[n * 256 + k] = (half_t)W2[k * 256 + n];
        }
    }
}

// ---------------- main: two s-groups per block, software-pipelined ----------------
// TERMINAL KERNEL (session conclusion). Structure = R2: per-ks interleave of
// {K-loop MFMA} with {build of next half / epilogue of prev half}, 2 blocks/CU.
// Measured: main 87.2 us, VALUBusy 48% (~= the 42 us VALU+trans issue floor for
// 134M mish evals), MfmaUtil 16% (overlapped), no spill (FETCH 11.4 MB).
// Structural constraint (measured 4x: R3/R4/R6-R7/R8): any schedule holding
// more concurrent state (2 accs + a gather array, or loop-carried prologue)
// exceeds the 128 unified-reg/thread budget at 2 blocks/CU and spills ~200+
// B/thread; 3 blocks/CU is LDS+reg infeasible; higher occupancy without the
// interleave (R1) is 8% slower. The granule swizzle is cost-neutral (R5 A/B)
// and omitted... kept here exactly as R2 benched (with swizzle) for fidelity.
#define CHUNK_US 528

__global__ __launch_bounds__(512, 4) void main_kernel(
        const float* __restrict__ obsWp, const half_t* __restrict__ actW,
        const half_t* __restrict__ W2T, const int* __restrict__ perm,
        const float* __restrict__ b1, const float* __restrict__ b2,
        const float* __restrict__ W3, const float* __restrict__ b3,
        float* __restrict__ out) {
    __shared__ __align__(16) ushort_t h1[2][32 * CHUNK_US];  // 66 KB
    __shared__ __align__(16) float obsb[256];
    __shared__ int perm_s[128];
    __shared__ float qpart[2][8][64];                        // 4 KB

    int t = threadIdx.x;
    int bid = blockIdx.x;
    int b = (bid & 7) * 64 + ((bid >> 3) & 63);   // XCD swizzle
    int sgp = bid >> 9;                            // 0..3
    int s0 = sgp * 16;

    int w = t >> 6;
    int L = t & 63;
    int lo = L & 15;
    int q = L >> 4;

    // ---- prologue: independent global loads issued ASAP ----
    const half_t* w2base = W2T + ((size_t)(w * 32 + lo)) * 256 + q * 8;
    half8_t bpre[4];
    bpre[0] = *reinterpret_cast<const half8_t*>(w2base + 0 * 4096 + 0 * 32);
    bpre[1] = *reinterpret_cast<const half8_t*>(w2base + 1 * 4096 + 0 * 32);
    bpre[2] = *reinterpret_cast<const half8_t*>(w2base + 0 * 4096 + 1 * 32);
    bpre[3] = *reinterpret_cast<const half8_t*>(w2base + 1 * 4096 + 1 * 32);

    int col0 = w * 32 + lo;
    int col1 = col0 + 16;
    fx2 b2p = {b2[col0] * LOG2E, b2[col1] * LOG2E};
    half2_t w3p = cvt_pk_f16(W3[col0] * LN2, W3[col1] * LN2);

    // per-thread perm rows (no barrier dependency): half h row = (b*64+s0+h*8+w)
    const int* prow = perm + ((size_t)b * 64 + s0 + w) * 8;
    int4 pa0 = *reinterpret_cast<const int4*>(prow);        // half0 j=0..3
    int4 pa1 = *reinterpret_cast<const int4*>(prow + 4);    // half0 j=4..7
    int4 pb0 = *reinterpret_cast<const int4*>(prow + 64);   // half1 j=0..3
    int4 pb1 = *reinterpret_cast<const int4*>(prow + 68);   // half1 j=4..7

    if (t < 256) {
        float s = b1[t];
#pragma unroll
        for (int c = 0; c < 8; ++c) s += obsWp[(size_t)c * 131072 + b * 256 + t];
        obsb[t] = s * LOG2E;
    } else if (t < 384) {
        perm_s[t - 256] = perm[((size_t)b * 64 + s0) * 8 + (t - 256)];
    }

    // build geometry: thread covers cols L*4..L*4+3 of rows (w*8+j)
    int g = L >> 1;
    int ksg = g >> 2;
    int qq = g & 3;
    int halfsel = L & 1;
    const half_t* actg = actW + (size_t)b * 64 * 256 + L * 4;
    int dstoff = qq * 128 + halfsel * 4 + ksg * CHUNK_US;

    // gather half-0 act rows NOW (in flight across B0)
    int pj0[8] = {pa0.x, pa0.y, pa0.z, pa0.w, pa1.x, pa1.y, pa1.z, pa1.w};
    uint2 av0[8];
#pragma unroll
    for (int j = 0; j < 8; ++j)
        av0[j] = *reinterpret_cast<const uint2*>(actg + (pj0[j] * 8 + j) * 256);

    // K-loop read offset with matching granule swizzle
    int phys = (q << 4) | ((lo + q) & 15);

    __syncthreads();   // B0: obsb/perm_s visible

    float4 ob = *reinterpret_cast<const float4*>(obsb + L * 4);

    // ---- build half 0 ----
    {
        fx2 r01 = {ob.x, ob.y};
        fx2 r23 = {ob.z, ob.w};
        ushort_t* dst0 = h1[0] + dstoff;
#pragma unroll
        for (int j = 0; j < 8; ++j) {
            half2_t a0 = __builtin_bit_cast(half2_t, av0[j].x);
            half2_t a1 = __builtin_bit_cast(half2_t, av0[j].y);
            r01 += (fx2){(float)a0.x, (float)a0.y};
            r23 += (fx2){(float)a1.x, (float)a1.y};
            fx2 h01 = mish2(r01);
            fx2 h23 = mish2(r23);
            int row = w * 8 + j;
            int mt2 = row >> 4, lr = row & 15;
            int lrs = (lr + qq) & 15;                        // swizzled granule
            uint2 pk = make_uint2(__builtin_bit_cast(unsigned, cvt_pk_f16(h01.x, h01.y)),
                                  __builtin_bit_cast(unsigned, cvt_pk_f16(h23.x, h23.y)));
            *reinterpret_cast<uint2*>(dst0 + mt2 * 8 * CHUNK_US + lrs * 8) = pk;
        }
    }

    // gather half-1 act rows (in flight across B1, hidden under K-loop-0 MFMAs)
    int pj1[8] = {pb0.x, pb0.y, pb0.z, pb0.w, pb1.x, pb1.y, pb1.z, pb1.w};
    uint2 av1[8];
#pragma unroll
    for (int j = 0; j < 8; ++j)
        av1[j] = *reinterpret_cast<const uint2*>(actg + (pj1[j] * 8 + j) * 256);

    __syncthreads();   // B1: h1[0] ready

    // ---- phase 1: K-loop(half0) interleaved with build(half1) ----
    floatx4 acc0[4][2];
#pragma unroll
    for (int mt = 0; mt < 4; ++mt)
#pragma unroll
        for (int nt = 0; nt < 2; ++nt) acc0[mt][nt] = (floatx4){0.f, 0.f, 0.f, 0.f};
    {
        fx2 r01 = {ob.x, ob.y};
        fx2 r23 = {ob.z, ob.w};
        ushort_t* dst1 = h1[1] + dstoff;
        const ushort_t* h1b0 = h1[0] + phys * 8;
#pragma unroll
        for (int ks = 0; ks < 8; ++ks) {
            half8_t afr[4];
#pragma unroll
            for (int mt = 0; mt < 4; ++mt)
                afr[mt] = *reinterpret_cast<const half8_t*>(h1b0 + (mt * 8 + ks) * CHUNK_US);
            half8_t bfr0 = (ks == 0) ? bpre[0] : (ks == 1) ? bpre[2]
                         : *reinterpret_cast<const half8_t*>(w2base + 0 * 4096 + ks * 32);
            half8_t bfr1 = (ks == 0) ? bpre[1] : (ks == 1) ? bpre[3]
                         : *reinterpret_cast<const half8_t*>(w2base + 1 * 4096 + ks * 32);
#pragma unroll
            for (int mt = 0; mt < 4; ++mt) {
                acc0[mt][0] = __builtin_amdgcn_mfma_f32_16x16x32_f16(afr[mt], bfr0, acc0[mt][0], 0, 0, 0);
                acc0[mt][1] = __builtin_amdgcn_mfma_f32_16x16x32_f16(afr[mt], bfr1, acc0[mt][1], 0, 0, 0);
            }
            // build1 step j=ks (VALU/trans fills MFMA shadow)
            {
                half2_t a0 = __builtin_bit_cast(half2_t, av1[ks].x);
                half2_t a1 = __builtin_bit_cast(half2_t, av1[ks].y);
                r01 += (fx2){(float)a0.x, (float)a0.y};
                r23 += (fx2){(float)a1.x, (float)a1.y};
                fx2 h01 = mish2(r01);
                fx2 h23 = mish2(r23);
                int row = w * 8 + ks;
                int mt2 = row >> 4, lr = row & 15;
                int lrs = (lr + qq) & 15;                    // swizzled granule
                uint2 pk = make_uint2(__builtin_bit_cast(unsigned, cvt_pk_f16(h01.x, h01.y)),
                                      __builtin_bit_cast(unsigned, cvt_pk_f16(h23.x, h23.y)));
                *reinterpret_cast<uint2*>(dst1 + mt2 * 8 * CHUNK_US + lrs * 8) = pk;
            }
        }
    }
    __syncthreads();   // B2: h1[1] ready, h1[0] consumed

    // ---- phase 2: K-loop(half1) interleaved with epilogue(half0) ----
    floatx4 acc1[4][2];
#pragma unroll
    for (int mt = 0; mt < 4; ++mt)
#pragma unroll
        for (int nt = 0; nt < 2; ++nt) acc1[mt][nt] = (floatx4){0.f, 0.f, 0.f, 0.f};
    {
        const ushort_t* h1b1 = h1[1] + phys * 8;
#pragma unroll
        for (int ks = 0; ks < 8; ++ks) {
            half8_t afr[4];
#pragma unroll
            for (int mt = 0; mt < 4; ++mt)
                afr[mt] = *reinterpret_cast<const half8_t*>(h1b1 + (mt * 8 + ks) * CHUNK_US);
            half8_t bfr0 = (ks == 0) ? bpre[0] : (ks == 1) ? bpre[2]
                         : *reinterpret_cast<const half8_t*>(w2base + 0 * 4096 + ks * 32);
            half8_t bfr1 = (ks == 0) ? bpre[1] : (ks == 1) ? bpre[3]
                         : *reinterpret_cast<const half8_t*>(w2base + 1 * 4096 + ks * 32);
#pragma unroll
            for (int mt = 0; mt < 4; ++mt) {
                acc1[mt][0] = __builtin_amdgcn_mfma_f32_16x16x32_f16(afr[mt], bfr0, acc1[mt][0], 0, 0, 0);
                acc1[mt][1] = __builtin_amdgcn_mfma_f32_16x16x32_f16(afr[mt], bfr1, acc1[mt][1], 0, 0, 0);
            }
            // epilogue(half0): 2 of 16 (mt,r) values per ks
#pragma unroll
            for (int v = 0; v < 2; ++v) {
                int idx = ks * 2 + v;
                int mt = idx >> 2, r = idx & 3;
                fx2 t2 = {acc0[mt][0][r], acc0[mt][1][r]};
                t2 += b2p;
                fx2 hh = mish2(t2);
                float part = fdot2_(cvt_pk_f16(hh.x, hh.y), w3p);
                float s = dpp_sum16(part);
                if (lo == 0) qpart[0][w][mt * 16 + q * 4 + r] = s;
            }
        }
    }
    // ---- epilogue(half1): wave-local (acc1 in regs), no barrier needed ----
#pragma unroll
    for (int idx = 0; idx < 16; ++idx) {
        int mt = idx >> 2, r = idx & 3;
        fx2 t2 = {acc1[mt][0][r], acc1[mt][1][r]};
        t2 += b2p;
        fx2 hh = mish2(t2);
        float part = fdot2_(cvt_pk_f16(hh.x, hh.y), w3p);
        float s = dpp_sum16(part);
        if (lo == 0) qpart[1][w][mt * 16 + q * 4 + r] = s;
    }
    __syncthreads();   // B3: all qpart visible

    // ---- final: reduce 8 waves, perm-gather, atomic ----
    if (t < 16) {
        int h = t >> 3, i = t & 7;
        float p = 0.f;
#pragma unroll
        for (int sl = 0; sl < 8; ++sl) {
            int k = perm_s[(h * 8 + sl) * 8 + i];
            int row = sl * 8 + k;
            float qv = b3[0];
#pragma unroll
            for (int ww = 0; ww < 8; ++ww) qv += qpart[h][ww][row];
            p += qv;
        }
        p *= (1.0f / 64.0f);
        atomicAdd(&out[b * 8 + i], p);
        atomicAdd(&out[4096 + b * 8 + i], p);
    }
}

extern "C" void kernel_launch(void* const* d_in, const int* in_sizes, int n_in,
                              void* d_out, int out_size, void* d_ws, size_t ws_size,
                              hipStream_t stream) {
    const float* state  = (const float*)d_in[0];
    const float* action = (const float*)d_in[1];
    const float* W1     = (const float*)d_in[2];
    const float* b1     = (const float*)d_in[3];
    const float* W2     = (const float*)d_in[4];
    const float* b2     = (const float*)d_in[5];
    const float* W3     = (const float*)d_in[6];
    const float* b3     = (const float*)d_in[7];
    const int*   perm   = (const int*)d_in[8];
    float* out = (float*)d_out;

    char* ws = (char*)d_ws;
    float*  obsWp = (float*)ws;                          // 8*512*256*4 = 4 MB
    half_t* actW  = (half_t*)(ws + 4194304);             // 16 MB
    half_t* W2T   = (half_t*)(ws + 4194304 + 16777216);  // 128 KB

    prep_kernel<<<1568, 256, 0, stream>>>(state, action, W1, W2, obsWp, actW, W2T, out);
    main_kernel<<<2048, 512, 0, stream>>>(obsWp, actW, W2T, perm, b1, b2, W3, b3, out);
}